// Round 2
// baseline (173.469 us; speedup 1.0000x reference)
//
#include <hip/hip_runtime.h>
#include <math.h>

#define F 128
#define H 64       // F/2
#define NBMOL 48
#define ATB 8      // atoms per block in atom kernel (4 per wave, 2 nets)
#define CAP 256    // LDS chunk capacity in pair kernel
#define SPLIT 16   // blocks per molecule in pair kernel

__device__ __forceinline__ float silu_f(float x) {
    return x / (1.0f + __expf(-x));
}
__device__ __forceinline__ float softplus_f(float x) {
    return fmaxf(x, 0.0f) + log1pf(__expf(-fabsf(x)));
}
__device__ __forceinline__ float frcp(float x) {
    return __builtin_amdgcn_rcpf(x);
}

// Kernel A v2: thread-per-(atom, hidden, net).
// Block 256 = 4 waves. Wave w: net = w&1 (0=q, 1=c), atom group g = w>>1
// (4 atoms). lane = hidden unit j. h0 activations are wave-uniform ->
// compiler emits s_load (scalar pipe); the only vector load per f-step is
// one coalesced 256B weight read, amortized over 4 atoms (4 indep FMA chains).
__global__ __launch_bounds__(256) void k_atom(
    const float* __restrict__ h0, const float* __restrict__ h1,
    const int* __restrict__ batch,
    const float* __restrict__ qW1, const float* __restrict__ qb1,
    const float* __restrict__ qW2, const float* __restrict__ qb2,
    const float* __restrict__ cW1, const float* __restrict__ cb1,
    const float* __restrict__ cW2, const float* __restrict__ cb2,
    const float* __restrict__ muW,
    float* __restrict__ q_raw, float* __restrict__ sqc6,
    float* __restrict__ mu,
    float* __restrict__ qsum, float* __restrict__ cnt,
    int* __restrict__ segstart, int* __restrict__ segend, int N)
{
    const int lane = threadIdx.x & 63;
    const int w = threadIdx.x >> 6;          // wave 0..3
    const int net = w & 1;                    // 0 = charge, 1 = c6
    const int g = w >> 1;                     // atom group 0..1
    const int a0 = blockIdx.x * ATB + g * 4;  // first atom of this wave

    const float* __restrict__ W1 = net ? cW1 : qW1;
    const float* __restrict__ b1 = net ? cb1 : qb1;
    const float* __restrict__ W2 = net ? cW2 : qW2;
    const float  b2v = net ? cb2[0] : qb2[0];

    // uniform row pointers (clamped so OOB atoms don't fault; stores guarded)
    const float* __restrict__ r0 = h0 + (size_t)min(a0 + 0, N - 1) * F;
    const float* __restrict__ r1 = h0 + (size_t)min(a0 + 1, N - 1) * F;
    const float* __restrict__ r2 = h0 + (size_t)min(a0 + 2, N - 1) * F;
    const float* __restrict__ r3 = h0 + (size_t)min(a0 + 3, N - 1) * F;

    float acc0 = b1[lane], acc1 = acc0, acc2 = acc0, acc3 = acc0;

    #pragma unroll 8
    for (int f = 0; f < F; ++f) {
        float wv = W1[f * H + lane];          // coalesced vector load
        acc0 = fmaf(r0[f], wv, acc0);         // r*[f] wave-uniform -> s_load
        acc1 = fmaf(r1[f], wv, acc1);
        acc2 = fmaf(r2[f], wv, acc2);
        acc3 = fmaf(r3[f], wv, acc3);
    }

    const float w2 = W2[lane];
    float v0 = silu_f(acc0) * w2;
    float v1 = silu_f(acc1) * w2;
    float v2 = silu_f(acc2) * w2;
    float v3 = silu_f(acc3) * w2;

    #pragma unroll
    for (int off = 32; off > 0; off >>= 1) {
        v0 += __shfl_xor(v0, off);
        v1 += __shfl_xor(v1, off);
        v2 += __shfl_xor(v2, off);
        v3 += __shfl_xor(v3, off);
    }

    float vals[4] = {v0, v1, v2, v3};
    #pragma unroll
    for (int a = 0; a < 4; ++a) {
        if (lane == a) {
            int i = a0 + a;
            if (i < N) {
                float s = vals[a] + b2v;
                if (net == 0) {
                    q_raw[i] = s;
                    int b = batch[i];
                    atomicAdd(&qsum[b], s);
                    atomicAdd(&cnt[b], 1.0f);
                    if (i == 0 || batch[i - 1] != b) segstart[b] = i;
                    if (i == N - 1 || batch[i + 1] != b) segend[b] = i + 1;
                } else {
                    sqc6[i] = sqrtf(softplus_f(s));
                }
            }
        }
    }

    // dipole: 24 (atom,d) dots per block, 6 per wave, coalesced b32 loads
    const int ab0 = blockIdx.x * ATB;
    const float mw0 = muW[lane], mw1 = muW[lane + 64];
    #pragma unroll
    for (int p = 0; p < 6; ++p) {
        int pr = w * 6 + p;        // 0..23
        int a = pr / 3, d = pr % 3;
        int i = ab0 + a;
        if (i < N) {
            const float* row = &h1[((size_t)i * 3 + d) * F];
            float pm = fmaf(row[lane], mw0, row[lane + 64] * mw1);
            #pragma unroll
            for (int off = 32; off > 0; off >>= 1) pm += __shfl_xor(pm, off);
            if (lane == 0) mu[i * 3 + d] = pm;
        }
    }
}

// Kernel B: pairwise energy. Grid (NBMOL, SPLIT); block 256 = 16 row-slots x
// 16 col-lanes. Molecule staged as SoA in LDS (conflict-free ds_read_b32).
__global__ __launch_bounds__(256) void k_pair(
    const float* __restrict__ pos,
    const float* __restrict__ q_raw, const float* __restrict__ sqc6,
    const float* __restrict__ mu,
    const float* __restrict__ qsum, const float* __restrict__ cnt,
    const int* __restrict__ segstart, const int* __restrict__ segend,
    float* __restrict__ out)
{
    const int b = blockIdx.x;
    const int s = blockIdx.y;
    const int st = segstart[b];
    const int n = segend[b] - st;
    const int tid = threadIdx.x;

    __shared__ float sq[CAP], sc[CAP], sx[CAP], sy[CAP], sz[CAP];
    __shared__ float smx[CAP], smy[CAP], smz[CAP];
    __shared__ float red[4];

    float e_c = 0.f, e_v = 0.f, e_d = 0.f;

    if (n > 1) {
        const float mean = qsum[b] / fmaxf(cnt[b], 1.0f);
        const int r = tid >> 4;   // row slot 0..15
        const int c = tid & 15;   // col lane 0..15
        for (int j0 = 0; j0 < n; j0 += CAP) {   // chunked: correct for any n
            const int chunk = min(CAP, n - j0);
            __syncthreads();
            for (int k = tid; k < chunk; k += 256) {
                int j = st + j0 + k;
                sq[k]  = q_raw[j] - mean;
                sc[k]  = sqc6[j];
                sx[k]  = pos[j * 3 + 0];
                sy[k]  = pos[j * 3 + 1];
                sz[k]  = pos[j * 3 + 2];
                smx[k] = mu[j * 3 + 0];
                smy[k] = mu[j * 3 + 1];
                smz[k] = mu[j * 3 + 2];
            }
            __syncthreads();
            for (int il = s + SPLIT * r; il < n; il += SPLIT * 16) {
                const int i = st + il;
                const float qi  = q_raw[i] - mean;
                const float sci = sqc6[i];
                const float xi = pos[i * 3], yi = pos[i * 3 + 1], zi = pos[i * 3 + 2];
                const float mxi = mu[i * 3], myi = mu[i * 3 + 1], mzi = mu[i * 3 + 2];
                for (int jl = c; jl < chunk; jl += 16) {
                    if (j0 + jl == il) continue;   // diagonal
                    float dx = xi - sx[jl], dy = yi - sy[jl], dz = zi - sz[jl];
                    float ds0 = fmaf(dx, dx, fmaf(dy, dy, dz * dz)); // dist_sq
                    float d   = sqrtf(ds0 + 1e-8f);                  // dist (+eps)
                    float inv_d = frcp(d);
                    // Coulomb: q_i q_j / d * (1 - exp(-d/2))
                    e_c = fmaf(qi * sq[jl] * inv_d, 1.0f - __expf(-0.5f * d), e_c);
                    // vdW: sqrt(c6_i c6_j) / (dist_sq^3 + 20)
                    float r6 = ds0 * ds0 * ds0;
                    e_v = fmaf(sci * sc[jl], frcp(r6 + 20.0f), e_v);
                    // dipole-dipole
                    float mdm  = fmaf(mxi, smx[jl], fmaf(myi, smy[jl], mzi * smz[jl]));
                    float mdni = fmaf(mxi, dx, fmaf(myi, dy, mzi * dz)) * inv_d;
                    float mdnj = fmaf(smx[jl], dx, fmaf(smy[jl], dy, smz[jl] * dz)) * inv_d;
                    e_d = fmaf(mdm - 3.0f * mdni * mdnj,
                               frcp(fmaf(ds0, d, 10.0f)), e_d);
                }
            }
        }
    }

    // energy = 0.5*14.399*E_coul - 0.5*E_vdw_mag + 0.5*E_dip
    float v = fmaf(7.1995f, e_c, fmaf(-0.5f, e_v, 0.5f * e_d));
    #pragma unroll
    for (int off = 32; off > 0; off >>= 1) v += __shfl_xor(v, off);
    __syncthreads();
    if ((tid & 63) == 0) red[tid >> 6] = v;
    __syncthreads();
    if (tid == 0) atomicAdd(out, red[0] + red[1] + red[2] + red[3]);
}

extern "C" void kernel_launch(void* const* d_in, const int* in_sizes, int n_in,
                              void* d_out, int out_size, void* d_ws, size_t ws_size,
                              hipStream_t stream) {
    const float* h0  = (const float*)d_in[0];
    const float* h1  = (const float*)d_in[1];
    const float* pos = (const float*)d_in[2];
    const int*   batch = (const int*)d_in[3];
    const float* qW1 = (const float*)d_in[4];
    const float* qb1 = (const float*)d_in[5];
    const float* qW2 = (const float*)d_in[6];
    const float* qb2 = (const float*)d_in[7];
    const float* cW1 = (const float*)d_in[8];
    const float* cb1 = (const float*)d_in[9];
    const float* cW2 = (const float*)d_in[10];
    const float* cb2 = (const float*)d_in[11];
    const float* muW = (const float*)d_in[12];
    float* out = (float*)d_out;
    const int N = in_sizes[0] / F;

    // workspace layout (floats): [qsum 48 | cnt 48 | segstart 48 | segend 48 |
    //                             pad to 256 | q_raw N | sqc6 N | mu 3N]
    float* ws = (float*)d_ws;
    float* qsum = ws;
    float* cnt  = ws + 48;
    int* segstart = (int*)(ws + 96);
    int* segend   = (int*)(ws + 144);
    float* q_raw = ws + 256;
    float* sqc6  = q_raw + N;
    float* mu    = sqc6 + N;

    hipMemsetAsync(ws, 0, 192 * sizeof(float), stream);
    hipMemsetAsync(out, 0, sizeof(float), stream);

    int nblk = (N + ATB - 1) / ATB;
    k_atom<<<nblk, 256, 0, stream>>>(h0, h1, batch, qW1, qb1, qW2, qb2,
                                     cW1, cb1, cW2, cb2, muW,
                                     q_raw, sqc6, mu, qsum, cnt,
                                     segstart, segend, N);
    k_pair<<<dim3(NBMOL, SPLIT), 256, 0, stream>>>(pos, q_raw, sqc6, mu,
                                                   qsum, cnt, segstart, segend,
                                                   out);
}

// Round 3
// 115.529 us; speedup vs baseline: 1.5015x; 1.5015x over previous
//
#include <hip/hip_runtime.h>
#include <math.h>

#define F 128
#define H 64       // F/2
#define NBMOL 48
#define ATB 16     // atoms per block in atom kernel (4 per wave)
#define CAP 256    // LDS chunk capacity in pair kernel
#define SPLIT 16   // blocks per molecule in pair kernel

__device__ __forceinline__ float silu_f(float x) {
    return x / (1.0f + __expf(-x));
}
__device__ __forceinline__ float softplus_f(float x) {
    return fmaxf(x, 0.0f) + log1pf(__expf(-fabsf(x)));
}
__device__ __forceinline__ float frcp(float x) {
    return __builtin_amdgcn_rcpf(x);
}

// Kernel A v3: wave = 4 atoms x BOTH nets; lane = hidden unit j.
// Weights staged once per block in LDS (64 KB); activations loaded via
// wave-uniform (readfirstlane-scalarized) float4 -> scalar pipe.
// No atomics, no memset dependencies: segment boundaries stored directly,
// q-mean is computed later in k_pair. Block 0 also zeroes out[0].
__global__ __launch_bounds__(256) void k_atom(
    const float* __restrict__ h0, const float* __restrict__ h1,
    const int* __restrict__ batch,
    const float* __restrict__ qW1, const float* __restrict__ qb1,
    const float* __restrict__ qW2, const float* __restrict__ qb2,
    const float* __restrict__ cW1, const float* __restrict__ cb1,
    const float* __restrict__ cW2, const float* __restrict__ cb2,
    const float* __restrict__ muW,
    float* __restrict__ q_raw, float* __restrict__ sqc6,
    float* __restrict__ mu,
    int* __restrict__ segstart, int* __restrict__ segend,
    float* __restrict__ out, int N)
{
    __shared__ float sW[2 * F * H];   // [0:8192) = qW1, [8192:16384) = cW1

    const int tid = threadIdx.x;
    if (blockIdx.x == 0 && tid == 0) out[0] = 0.0f;

    for (int k = tid; k < F * H; k += 256) {   // coalesced, conflict-free
        sW[k]         = qW1[k];
        sW[F * H + k] = cW1[k];
    }
    __syncthreads();

    const int lane = tid & 63;
    const int w = tid >> 6;
    int a0 = __builtin_amdgcn_readfirstlane(blockIdx.x * ATB + w * 4);

    const float4* __restrict__ r0 = (const float4*)(h0 + (size_t)(a0 + 0) * F);
    const float4* __restrict__ r1 = (const float4*)(h0 + (size_t)(a0 + 1) * F);
    const float4* __restrict__ r2 = (const float4*)(h0 + (size_t)(a0 + 2) * F);
    const float4* __restrict__ r3 = (const float4*)(h0 + (size_t)(a0 + 3) * F);

    float aq0, aq1, aq2, aq3, ac0, ac1, ac2, ac3;
    aq0 = aq1 = aq2 = aq3 = qb1[lane];
    ac0 = ac1 = ac2 = ac3 = cb1[lane];

    #pragma unroll 2
    for (int fb = 0; fb < F / 4; ++fb) {
        float4 x0 = r0[fb], x1 = r1[fb], x2 = r2[fb], x3 = r3[fb];
        const float* wq = &sW[fb * 256 + lane];          // (4fb+s)*64+lane
        const float* wc = &sW[F * H + fb * 256 + lane];
        #define STEP(comp, s) { \
            float wqs = wq[(s) * 64], wcs = wc[(s) * 64]; \
            aq0 = fmaf(x0.comp, wqs, aq0); ac0 = fmaf(x0.comp, wcs, ac0); \
            aq1 = fmaf(x1.comp, wqs, aq1); ac1 = fmaf(x1.comp, wcs, ac1); \
            aq2 = fmaf(x2.comp, wqs, aq2); ac2 = fmaf(x2.comp, wcs, ac2); \
            aq3 = fmaf(x3.comp, wqs, aq3); ac3 = fmaf(x3.comp, wcs, ac3); }
        STEP(x, 0) STEP(y, 1) STEP(z, 2) STEP(w, 3)
        #undef STEP
    }

    const float w2q = qW2[lane], w2c = cW2[lane];
    float vq0 = silu_f(aq0) * w2q, vq1 = silu_f(aq1) * w2q;
    float vq2 = silu_f(aq2) * w2q, vq3 = silu_f(aq3) * w2q;
    float vc0 = silu_f(ac0) * w2c, vc1 = silu_f(ac1) * w2c;
    float vc2 = silu_f(ac2) * w2c, vc3 = silu_f(ac3) * w2c;

    #pragma unroll
    for (int off = 32; off > 0; off >>= 1) {
        vq0 += __shfl_xor(vq0, off); vq1 += __shfl_xor(vq1, off);
        vq2 += __shfl_xor(vq2, off); vq3 += __shfl_xor(vq3, off);
        vc0 += __shfl_xor(vc0, off); vc1 += __shfl_xor(vc1, off);
        vc2 += __shfl_xor(vc2, off); vc3 += __shfl_xor(vc3, off);
    }

    const float qb2v = qb2[0], cb2v = cb2[0];
    float vqs[4] = {vq0, vq1, vq2, vq3};
    float vcs[4] = {vc0, vc1, vc2, vc3};
    #pragma unroll
    for (int a = 0; a < 4; ++a) {
        if (lane == a) {
            int i = a0 + a;
            if (i < N) {
                q_raw[i] = vqs[a] + qb2v;
                sqc6[i]  = sqrtf(softplus_f(vcs[a] + cb2v));
                int b = batch[i];
                if (i == 0 || batch[i - 1] != b) segstart[b] = i;
                if (i == N - 1 || batch[i + 1] != b) segend[b] = i + 1;
            }
        }
    }

    // dipole: wave w handles atoms w*4..w*4+3, 3 components each (12 rows)
    const float2 mw = *(const float2*)&muW[2 * lane];
    const int ab0 = blockIdx.x * ATB;
    #pragma unroll
    for (int a = 0; a < 4; ++a) {
        int i = ab0 + w * 4 + a;
        if (i < N) {
            #pragma unroll
            for (int d = 0; d < 3; ++d) {
                const float2* rowv = (const float2*)&h1[((size_t)i * 3 + d) * F];
                float2 hv = rowv[lane];
                float pm = fmaf(hv.x, mw.x, hv.y * mw.y);
                #pragma unroll
                for (int off = 32; off > 0; off >>= 1) pm += __shfl_xor(pm, off);
                if (lane == 0) mu[i * 3 + d] = pm;
            }
        }
    }
}

// Kernel B v3: pairwise energy. Grid (NBMOL, SPLIT); block 256.
// Computes q-mean locally (block scan of q_raw), stages molecule SoA in LDS;
// fast path (n <= CAP) reads i-rows from LDS too.
__global__ __launch_bounds__(256) void k_pair(
    const float* __restrict__ pos,
    const float* __restrict__ q_raw, const float* __restrict__ sqc6,
    const float* __restrict__ mu,
    const int* __restrict__ segstart, const int* __restrict__ segend,
    float* __restrict__ out)
{
    const int b = blockIdx.x;
    const int s = blockIdx.y;
    const int tid = threadIdx.x;
    const int st = segstart[b];
    const int n = segend[b] - st;

    __shared__ float sq[CAP], sc[CAP], sx[CAP], sy[CAP], sz[CAP];
    __shared__ float smx[CAP], smy[CAP], smz[CAP];
    __shared__ float red[4];

    float e_c = 0.f, e_v = 0.f, e_d = 0.f;

    if (n > 1) {
        // per-molecule mean charge (block-redundant, cheap)
        float part = 0.f;
        for (int k = tid; k < n; k += 256) part += q_raw[st + k];
        #pragma unroll
        for (int off = 32; off > 0; off >>= 1) part += __shfl_xor(part, off);
        if ((tid & 63) == 0) red[tid >> 6] = part;
        __syncthreads();
        const float mean = (red[0] + red[1] + red[2] + red[3]) / (float)n;
        const int r = tid >> 4;   // row slot 0..15
        const int c = tid & 15;   // col lane 0..15

        #define PAIR_MATH(qi, sci, xi, yi, zi, mxi, myi, mzi, jl)            \
            {                                                                 \
                float dx = xi - sx[jl], dy = yi - sy[jl], dz = zi - sz[jl];   \
                float ds0 = fmaf(dx, dx, fmaf(dy, dy, dz * dz));              \
                float d = sqrtf(ds0 + 1e-8f);                                 \
                float inv_d = frcp(d);                                        \
                e_c = fmaf(qi * sq[jl] * inv_d,                               \
                           1.0f - __expf(-0.5f * d), e_c);                    \
                float r6 = ds0 * ds0 * ds0;                                   \
                e_v = fmaf(sci * sc[jl], frcp(r6 + 20.0f), e_v);              \
                float mdm = fmaf(mxi, smx[jl], fmaf(myi, smy[jl],             \
                                                    mzi * smz[jl]));          \
                float mdni = fmaf(mxi, dx, fmaf(myi, dy, mzi * dz)) * inv_d;  \
                float mdnj = fmaf(smx[jl], dx, fmaf(smy[jl], dy,              \
                                                    smz[jl] * dz)) * inv_d;   \
                e_d = fmaf(mdm - 3.0f * mdni * mdnj,                          \
                           frcp(fmaf(ds0, d, 10.0f)), e_d);                   \
            }

        if (n <= CAP) {
            __syncthreads();
            for (int k = tid; k < n; k += 256) {
                int j = st + k;
                sq[k]  = q_raw[j] - mean;
                sc[k]  = sqc6[j];
                sx[k]  = pos[j * 3 + 0];
                sy[k]  = pos[j * 3 + 1];
                sz[k]  = pos[j * 3 + 2];
                smx[k] = mu[j * 3 + 0];
                smy[k] = mu[j * 3 + 1];
                smz[k] = mu[j * 3 + 2];
            }
            __syncthreads();
            for (int il = s + SPLIT * r; il < n; il += SPLIT * 16) {
                const float qi = sq[il], sci = sc[il];
                const float xi = sx[il], yi = sy[il], zi = sz[il];
                const float mxi = smx[il], myi = smy[il], mzi = smz[il];
                for (int jl = c; jl < n; jl += 16) {
                    if (jl == il) continue;
                    PAIR_MATH(qi, sci, xi, yi, zi, mxi, myi, mzi, jl)
                }
            }
        } else {
            for (int j0 = 0; j0 < n; j0 += CAP) {
                const int chunk = min(CAP, n - j0);
                __syncthreads();
                for (int k = tid; k < chunk; k += 256) {
                    int j = st + j0 + k;
                    sq[k]  = q_raw[j] - mean;
                    sc[k]  = sqc6[j];
                    sx[k]  = pos[j * 3 + 0];
                    sy[k]  = pos[j * 3 + 1];
                    sz[k]  = pos[j * 3 + 2];
                    smx[k] = mu[j * 3 + 0];
                    smy[k] = mu[j * 3 + 1];
                    smz[k] = mu[j * 3 + 2];
                }
                __syncthreads();
                for (int il = s + SPLIT * r; il < n; il += SPLIT * 16) {
                    const int i = st + il;
                    const float qi = q_raw[i] - mean;
                    const float sci = sqc6[i];
                    const float xi = pos[i * 3], yi = pos[i * 3 + 1],
                                zi = pos[i * 3 + 2];
                    const float mxi = mu[i * 3], myi = mu[i * 3 + 1],
                                mzi = mu[i * 3 + 2];
                    for (int jl = c; jl < chunk; jl += 16) {
                        if (j0 + jl == il) continue;
                        PAIR_MATH(qi, sci, xi, yi, zi, mxi, myi, mzi, jl)
                    }
                }
            }
        }
        #undef PAIR_MATH
    }

    // energy = 0.5*14.399*E_coul - 0.5*E_vdw_mag + 0.5*E_dip
    float v = fmaf(7.1995f, e_c, fmaf(-0.5f, e_v, 0.5f * e_d));
    #pragma unroll
    for (int off = 32; off > 0; off >>= 1) v += __shfl_xor(v, off);
    __syncthreads();
    if ((tid & 63) == 0) red[tid >> 6] = v;
    __syncthreads();
    if (tid == 0) atomicAdd(out, red[0] + red[1] + red[2] + red[3]);
}

extern "C" void kernel_launch(void* const* d_in, const int* in_sizes, int n_in,
                              void* d_out, int out_size, void* d_ws, size_t ws_size,
                              hipStream_t stream) {
    const float* h0  = (const float*)d_in[0];
    const float* h1  = (const float*)d_in[1];
    const float* pos = (const float*)d_in[2];
    const int*   batch = (const int*)d_in[3];
    const float* qW1 = (const float*)d_in[4];
    const float* qb1 = (const float*)d_in[5];
    const float* qW2 = (const float*)d_in[6];
    const float* qb2 = (const float*)d_in[7];
    const float* cW1 = (const float*)d_in[8];
    const float* cb1 = (const float*)d_in[9];
    const float* cW2 = (const float*)d_in[10];
    const float* cb2 = (const float*)d_in[11];
    const float* muW = (const float*)d_in[12];
    float* out = (float*)d_out;
    const int N = in_sizes[0] / F;

    // workspace layout (floats): [segstart 48 | segend 48 | pad to 128 |
    //                             q_raw N | sqc6 N | mu 3N]
    float* ws = (float*)d_ws;
    int* segstart = (int*)ws;
    int* segend   = (int*)(ws + 48);
    float* q_raw = ws + 128;
    float* sqc6  = q_raw + N;
    float* mu    = sqc6 + N;

    int nblk = (N + ATB - 1) / ATB;
    k_atom<<<nblk, 256, 0, stream>>>(h0, h1, batch, qW1, qb1, qW2, qb2,
                                     cW1, cb1, cW2, cb2, muW,
                                     q_raw, sqc6, mu, segstart, segend,
                                     out, N);
    k_pair<<<dim3(NBMOL, SPLIT), 256, 0, stream>>>(pos, q_raw, sqc6, mu,
                                                   segstart, segend, out);
}